// Round 1
// baseline (1327.319 us; speedup 1.0000x reference)
//
#include <hip/hip_runtime.h>
#include <hip/hip_bf16.h>

#define WID 256
#define HEADS 8
#define DH 32
#define EPS_GN 1e-5f

// ---------- transpose 3 256x256 matrices into workspace ----------
__global__ void transpose3_k(const float* __restrict__ A, const float* __restrict__ B,
                             const float* __restrict__ C, float* __restrict__ AT,
                             float* __restrict__ BT, float* __restrict__ CT) {
    __shared__ float tile[32][33];
    const float* src = (blockIdx.z == 0) ? A : (blockIdx.z == 1) ? B : C;
    float* dst = (blockIdx.z == 0) ? AT : (blockIdx.z == 1) ? BT : CT;
    int bx = blockIdx.x * 32, by = blockIdx.y * 32;
    int tx = threadIdx.x & 31, ty = threadIdx.x >> 5;  // ty in 0..7
#pragma unroll
    for (int i = 0; i < 32; i += 8)
        tile[ty + i][tx] = src[(by + ty + i) * WID + bx + tx];
    __syncthreads();
#pragma unroll
    for (int i = 0; i < 32; i += 8)
        dst[(bx + ty + i) * WID + by + tx] = tile[tx][ty + i];
}

// ---------- node projections: xs = x@Wsrc^T, xt = x@Wtgt^T ----------
__global__ __launch_bounds__(256, 2)
void proj_k(const float* __restrict__ x, const float* __restrict__ WsT,
            const float* __restrict__ WtT, float* __restrict__ xs,
            float* __restrict__ xt, int N) {
    __shared__ float xtile[WID * 36];  // [k][n], stride 36 (alignment + fewer write conflicts)
    int n0 = blockIdx.x * 32;
    int t = threadIdx.x;
    int nn = min(32, N - n0);
    for (int n = 0; n < nn; n++)
        xtile[t * 36 + n] = x[(size_t)(n0 + n) * WID + t];
    __syncthreads();
    float accS[32], accT[32];
#pragma unroll
    for (int n = 0; n < 32; n++) { accS[n] = 0.f; accT[n] = 0.f; }
    for (int k = 0; k < WID; k++) {
        float ws = WsT[k * WID + t];
        float wt = WtT[k * WID + t];
        const float4* xp = (const float4*)&xtile[k * 36];
#pragma unroll
        for (int q = 0; q < 8; q++) {
            float4 xv = xp[q];
            accS[q * 4 + 0] += xv.x * ws; accT[q * 4 + 0] += xv.x * wt;
            accS[q * 4 + 1] += xv.y * ws; accT[q * 4 + 1] += xv.y * wt;
            accS[q * 4 + 2] += xv.z * ws; accT[q * 4 + 2] += xv.z * wt;
            accS[q * 4 + 3] += xv.w * ws; accT[q * 4 + 3] += xv.w * wt;
        }
    }
    for (int n = 0; n < nn; n++) {
        xs[(size_t)(n0 + n) * WID + t] = accS[n];
        xt[(size_t)(n0 + n) * WID + t] = accT[n];
    }
}

// ---------- fused edge pipeline: gather -> GN -> bag bias -> gate/val -> W_post -> atomic scatter ----------
__global__ __launch_bounds__(256, 2)
void edge_k(const float* __restrict__ xs, const float* __restrict__ xt,
            const int* __restrict__ eidx, const int* __restrict__ eattr,
            const float* __restrict__ emb, const float* __restrict__ Wg,
            const float* __restrict__ Wv, const float* __restrict__ WpT,
            float* __restrict__ agg, int E) {
    __shared__ float xbias[16384];  // [0..8191]=xbuf[32][256], [8192..16383]=bias[32][256]; act_t[256][36] aliases front
    __shared__ float mean_s[256], rstd_s[256];
    __shared__ int src_s[32], tgt_s[32], attr_s[96];
    float* xbuf = xbias;
    float* bias = xbias + 8192;
    float* act_t = xbias;

    int t = threadIdx.x;
    int e0 = blockIdx.x * 32;
    int ne = min(32, E - e0);

    if (t < 32 && t < ne) { src_s[t] = eidx[e0 + t]; tgt_s[t] = eidx[E + e0 + t]; }
    if (t < 96 && t < ne * 3) attr_s[t] = eattr[(size_t)e0 * 3 + t];
    __syncthreads();

    // P1: gather xs[src] + xt[tgt] -> xbuf
    for (int e = 0; e < ne; e++) {
        int s = src_s[e], g = tgt_s[e];
        xbuf[e * WID + t] = xs[(size_t)s * WID + t] + xt[(size_t)g * WID + t];
    }
    __syncthreads();

    // P2: group stats, one (e,h) pair per thread; rotated reads -> conflict-free
    {
        int base = t * 32;
        float sum = 0.f, sq = 0.f;
#pragma unroll
        for (int i = 0; i < 32; i++) {
            int d = (t + i) & 31;
            float v = xbuf[base + d];
            sum += v; sq += v * v;
        }
        float mu = sum * (1.f / 32.f);
        float var = sq * (1.f / 32.f) - mu * mu;
        mean_s[t] = mu;
        rstd_s[t] = rsqrtf(var + EPS_GN);
    }
    // P2b: embedding-bag bias (emb[0] is the zero padding row; count excludes idx==0)
    for (int e = 0; e < ne; e++) {
        float b = 0.f; int cnt = 0;
#pragma unroll
        for (int c = 0; c < 3; c++) {
            int idx = attr_s[e * 3 + c];
            if (idx != 0) { b += emb[idx * WID + t]; cnt++; }
        }
        bias[e * WID + t] = b / (float)max(cnt, 1);
    }
    __syncthreads();

    // P4: normalize in place
    {
        int h = t >> 5;
        for (int e = 0; e < ne; e++) {
            int si = e * 8 + h;
            xbuf[e * WID + t] = (xbuf[e * WID + t] - mean_s[si]) * rstd_s[si];
        }
    }
    __syncthreads();

    // P5: gate/val per-head 32x32 matmuls; thread t owns (h=t>>5, f=t&31)
    float acc[32];
    {
        const float4* wgp = (const float4*)(Wg + t * 32);
        const float4* wvp = (const float4*)(Wv + t * 32);
        float4 wg[8], wv[8];
#pragma unroll
        for (int q = 0; q < 8; q++) { wg[q] = wgp[q]; wv[q] = wvp[q]; }
        int h = t >> 5;
#pragma unroll
        for (int e = 0; e < 32; e++) acc[e] = 0.f;
        for (int e = 0; e < ne; e++) {
            const float4* xp = (const float4*)&xbuf[e * WID + h * 32];
            const float4* bp = (const float4*)&bias[e * WID + h * 32];
            float g = 0.f, v = 0.f;
#pragma unroll
            for (int q = 0; q < 8; q++) {
                float4 xv = xp[q], bv = bp[q];
                g += (xv.x + bv.x) * wg[q].x + (xv.y + bv.y) * wg[q].y
                   + (xv.z + bv.z) * wg[q].z + (xv.w + bv.w) * wg[q].w;
                v += xv.x * wv[q].x + xv.y * wv[q].y + xv.z * wv[q].z + xv.w * wv[q].w;
            }
            acc[e] = fmaxf(g, 0.f) * v;
        }
    }
    __syncthreads();  // all P5 reads of xbuf/bias complete
    // act transposed to [k=t][e], stride 36 (float4-aligned rows)
#pragma unroll
    for (int e = 0; e < 32; e++) act_t[t * 36 + e] = acc[e];
    __syncthreads();

    // P6: out_e = act @ Wpost^T; thread t -> 4 cols (j0 + 64*jj) x 8 edges (eg*8+ee)
    {
        int j0 = t & 63, eg = t >> 6;
        float o[4][8];
#pragma unroll
        for (int jj = 0; jj < 4; jj++)
#pragma unroll
            for (int ee = 0; ee < 8; ee++) o[jj][ee] = 0.f;
        for (int k = 0; k < WID; k++) {
            float w0 = WpT[k * WID + j0];
            float w1 = WpT[k * WID + j0 + 64];
            float w2 = WpT[k * WID + j0 + 128];
            float w3 = WpT[k * WID + j0 + 192];
            const float4* ap = (const float4*)&act_t[k * 36 + eg * 8];
            float4 a0 = ap[0], a1 = ap[1];
            float av[8] = {a0.x, a0.y, a0.z, a0.w, a1.x, a1.y, a1.z, a1.w};
#pragma unroll
            for (int ee = 0; ee < 8; ee++) {
                o[0][ee] += w0 * av[ee];
                o[1][ee] += w1 * av[ee];
                o[2][ee] += w2 * av[ee];
                o[3][ee] += w3 * av[ee];
            }
        }
#pragma unroll
        for (int ee = 0; ee < 8; ee++) {
            int e = eg * 8 + ee;
            if (e < ne) {
                int node = tgt_s[e];
                float* dst = agg + (size_t)node * WID + j0;
                atomicAdd(dst, o[0][ee]);
                atomicAdd(dst + 64, o[1][ee]);
                atomicAdd(dst + 128, o[2][ee]);
                atomicAdd(dst + 192, o[3][ee]);
            }
        }
    }
}

// ---------- final degree rescale ----------
__global__ void rescale_k(const float* __restrict__ agg, const float* __restrict__ deg,
                          const float* __restrict__ dp, float* __restrict__ out, int N) {
    int n = blockIdx.x;
    int j = threadIdx.x;
    float d = deg[n];
    float p = dp[j];
    out[(size_t)n * WID + j] = powf(d, p) * agg[(size_t)n * WID + j];
}

extern "C" void kernel_launch(void* const* d_in, const int* in_sizes, int n_in,
                              void* d_out, int out_size, void* d_ws, size_t ws_size,
                              hipStream_t stream) {
    const float* x    = (const float*)d_in[0];
    const float* deg  = (const float*)d_in[1];
    const int*   eidx = (const int*)d_in[2];
    const int*   eatt = (const int*)d_in[3];
    const float* Wsrc = (const float*)d_in[4];
    const float* Wtgt = (const float*)d_in[5];
    const float* emb  = (const float*)d_in[6];
    const float* Wg   = (const float*)d_in[7];
    const float* Wv   = (const float*)d_in[8];
    const float* Wp   = (const float*)d_in[9];
    const float* dp   = (const float*)d_in[10];
    int N = in_sizes[0] / WID;
    int E = in_sizes[2] / 2;

    float* ws  = (float*)d_ws;
    float* xs  = ws;                           // N*W
    float* xt  = xs + (size_t)N * WID;         // N*W
    float* agg = xt + (size_t)N * WID;         // N*W
    float* WsT = agg + (size_t)N * WID;        // W*W
    float* WtT = WsT + WID * WID;              // W*W
    float* WpT = WtT + WID * WID;              // W*W

    hipMemsetAsync(agg, 0, (size_t)N * WID * sizeof(float), stream);
    transpose3_k<<<dim3(8, 8, 3), 256, 0, stream>>>(Wsrc, Wtgt, Wp, WsT, WtT, WpT);
    proj_k<<<(N + 31) / 32, 256, 0, stream>>>(x, WsT, WtT, xs, xt, N);
    edge_k<<<(E + 31) / 32, 256, 0, stream>>>(xs, xt, eidx, eatt, emb, Wg, Wv, WpT, agg, E);
    rescale_k<<<N, 256, 0, stream>>>(agg, deg, dp, (float*)d_out, N);
}

// Round 2
// 713.105 us; speedup vs baseline: 1.8613x; 1.8613x over previous
//
#include <hip/hip_runtime.h>

#define WID 256
#define EPS_GN 1e-5f

typedef __bf16 v8bf __attribute__((ext_vector_type(8)));
typedef float  v4f  __attribute__((ext_vector_type(4)));

__device__ inline unsigned short f2b(float f) {
    unsigned int u = __builtin_bit_cast(unsigned int, f);
    unsigned int r = (u + 0x7fffu + ((u >> 16) & 1u)) >> 16;
    return (unsigned short)r;
}

// ---------- transpose Wsrc, Wtgt into workspace (for proj_k) ----------
__global__ void transpose2_k(const float* __restrict__ A, const float* __restrict__ B,
                             float* __restrict__ AT, float* __restrict__ BT) {
    __shared__ float tile[32][33];
    const float* src = (blockIdx.z == 0) ? A : B;
    float* dst = (blockIdx.z == 0) ? AT : BT;
    int bx = blockIdx.x * 32, by = blockIdx.y * 32;
    int tx = threadIdx.x & 31, ty = threadIdx.x >> 5;
#pragma unroll
    for (int i = 0; i < 32; i += 8)
        tile[ty + i][tx] = src[(by + ty + i) * WID + bx + tx];
    __syncthreads();
#pragma unroll
    for (int i = 0; i < 32; i += 8)
        dst[(bx + ty + i) * WID + by + tx] = tile[tx][ty + i];
}

// ---------- cast Wp / Wg / Wv to bf16 ----------
__global__ void cast_k(const float* __restrict__ Wp, const float* __restrict__ Wg,
                       const float* __restrict__ Wv, unsigned short* __restrict__ Wpb,
                       unsigned short* __restrict__ Wgb, unsigned short* __restrict__ Wvb) {
    int i = blockIdx.x * 256 + threadIdx.x;
    if (i < 65536) Wpb[i] = f2b(Wp[i]);
    if (i < 8192) { Wgb[i] = f2b(Wg[i]); Wvb[i] = f2b(Wv[i]); }
}

// ---------- node projections: xs = x@Wsrc^T, xt = x@Wtgt^T ----------
__global__ __launch_bounds__(256, 2)
void proj_k(const float* __restrict__ x, const float* __restrict__ WsT,
            const float* __restrict__ WtT, float* __restrict__ xs,
            float* __restrict__ xt, int N) {
    __shared__ float xtile[WID * 36];
    int n0 = blockIdx.x * 32;
    int t = threadIdx.x;
    int nn = min(32, N - n0);
    for (int n = 0; n < nn; n++)
        xtile[t * 36 + n] = x[(size_t)(n0 + n) * WID + t];
    __syncthreads();
    float accS[32], accT[32];
#pragma unroll
    for (int n = 0; n < 32; n++) { accS[n] = 0.f; accT[n] = 0.f; }
    for (int k = 0; k < WID; k++) {
        float ws = WsT[k * WID + t];
        float wt = WtT[k * WID + t];
        const float4* xp = (const float4*)&xtile[k * 36];
#pragma unroll
        for (int q = 0; q < 8; q++) {
            float4 xv = xp[q];
            accS[q * 4 + 0] += xv.x * ws; accT[q * 4 + 0] += xv.x * wt;
            accS[q * 4 + 1] += xv.y * ws; accT[q * 4 + 1] += xv.y * wt;
            accS[q * 4 + 2] += xv.z * ws; accT[q * 4 + 2] += xv.z * wt;
            accS[q * 4 + 3] += xv.w * ws; accT[q * 4 + 3] += xv.w * wt;
        }
    }
    for (int n = 0; n < nn; n++) {
        xs[(size_t)(n0 + n) * WID + t] = accS[n];
        xt[(size_t)(n0 + n) * WID + t] = accT[n];
    }
}

// ---------- fused edge pipeline, MFMA version ----------
__global__ __launch_bounds__(256, 2)
void edge_k(const float* __restrict__ xs, const float* __restrict__ xt,
            const int* __restrict__ eidx, const int* __restrict__ eattr,
            const float* __restrict__ emb, const unsigned short* __restrict__ Wgb,
            const unsigned short* __restrict__ Wvb, const unsigned short* __restrict__ Wpb,
            float* __restrict__ agg, int E) {
    __shared__ float xx[32 * 256];            // 32 KB; aliased as actb after P4
    __shared__ unsigned short xnb[32 * 264];  // bf16 xn, row stride 264
    __shared__ unsigned short ginb[32 * 264]; // bf16 xn + bag-bias
    __shared__ float mu_s[256], rs_s[256];
    __shared__ int src_s[32], tgt_s[32], attr_s[96];
    unsigned short* actb = (unsigned short*)xx; // 32x264 bf16 act, reuses xx region

    int t = threadIdx.x;
    int e0 = blockIdx.x * 32;
    int ne = min(32, E - e0);

    if (t < 32) { src_s[t] = (t < ne) ? eidx[e0 + t] : 0;
                  tgt_s[t] = (t < ne) ? eidx[E + e0 + t] : 0; }
    if (t < 96) attr_s[t] = (t < ne * 3) ? eattr[(size_t)e0 * 3 + t] : 0;
    __syncthreads();

    // P1: gather xs[src] + xt[tgt] -> xx  (thread t owns column t)
    for (int e = 0; e < 32; e++) {
        int s = src_s[e], g = tgt_s[e];
        float v = xs[(size_t)s * WID + t] + xt[(size_t)g * WID + t];
        xx[e * WID + t] = (e < ne) ? v : 0.f;
    }
    __syncthreads();

    // P2: group stats, one (e,h) pair per thread (p = t = e*8+h), rotated reads
    {
        int base = t * 32;
        float sum = 0.f, sq = 0.f;
#pragma unroll
        for (int i = 0; i < 32; i++) {
            int d = (t + i) & 31;
            float v = xx[base + d];
            sum += v; sq += v * v;
        }
        float mu = sum * (1.f / 32.f);
        float var = sq * (1.f / 32.f) - mu * mu;
        mu_s[t] = mu;
        rs_s[t] = rsqrtf(var + EPS_GN);
    }
    __syncthreads();

    // P4: normalize + embedding-bag bias, write bf16 xn and gin (column t)
    {
        int h = t >> 5;
        for (int e = 0; e < 32; e++) {
            int si = e * 8 + h;
            float xn = (xx[e * WID + t] - mu_s[si]) * rs_s[si];
            float b = 0.f; int cnt = 0;
#pragma unroll
            for (int c = 0; c < 3; c++) {
                int idx = attr_s[e * 3 + c];
                if (idx != 0) { b += emb[idx * WID + t]; cnt++; }
            }
            b *= (cnt > 0) ? (1.f / (float)cnt) : 1.f;
            xnb[e * 264 + t] = f2b(xn);
            ginb[e * 264 + t] = f2b(xn + b);
        }
    }
    __syncthreads();

    // P5: gate/val per-head MFMA. wave w handles heads 2w, 2w+1.
    // act[e][h*32+f] = relu(gate)*val, stored bf16 into actb.
    {
        int w = t >> 6, lane = t & 63;
        int m = lane & 15;     // A row / B col within tile
        int kg = lane >> 4;    // k-chunk 0..3
#pragma unroll
        for (int hh = 0; hh < 2; hh++) {
            int h = w * 2 + hh;
            // A frags (2 M-tiles) for val (xn) and gate (gin)
            v8bf av0 = *(const v8bf*)&xnb[(m) * 264 + h * 32 + kg * 8];
            v8bf av1 = *(const v8bf*)&xnb[(16 + m) * 264 + h * 32 + kg * 8];
            v8bf ag0 = *(const v8bf*)&ginb[(m) * 264 + h * 32 + kg * 8];
            v8bf ag1 = *(const v8bf*)&ginb[(16 + m) * 264 + h * 32 + kg * 8];
            // B frags (2 N-tiles each): B[d][f] = W[h][f][d] -> rows of W, contiguous d
            v8bf bg0 = *(const v8bf*)&Wgb[h * 1024 + (m) * 32 + kg * 8];
            v8bf bg1 = *(const v8bf*)&Wgb[h * 1024 + (16 + m) * 32 + kg * 8];
            v8bf bv0 = *(const v8bf*)&Wvb[h * 1024 + (m) * 32 + kg * 8];
            v8bf bv1 = *(const v8bf*)&Wvb[h * 1024 + (16 + m) * 32 + kg * 8];
            v4f z = {0.f, 0.f, 0.f, 0.f};
            v4f g00 = __builtin_amdgcn_mfma_f32_16x16x32_bf16(ag0, bg0, z, 0, 0, 0);
            v4f g01 = __builtin_amdgcn_mfma_f32_16x16x32_bf16(ag0, bg1, z, 0, 0, 0);
            v4f g10 = __builtin_amdgcn_mfma_f32_16x16x32_bf16(ag1, bg0, z, 0, 0, 0);
            v4f g11 = __builtin_amdgcn_mfma_f32_16x16x32_bf16(ag1, bg1, z, 0, 0, 0);
            v4f v00 = __builtin_amdgcn_mfma_f32_16x16x32_bf16(av0, bv0, z, 0, 0, 0);
            v4f v01 = __builtin_amdgcn_mfma_f32_16x16x32_bf16(av0, bv1, z, 0, 0, 0);
            v4f v10 = __builtin_amdgcn_mfma_f32_16x16x32_bf16(av1, bv0, z, 0, 0, 0);
            v4f v11 = __builtin_amdgcn_mfma_f32_16x16x32_bf16(av1, bv1, z, 0, 0, 0);
            // wait until all P5 LDS reads from xx-alias are irrelevant: actb aliases xx (dead),
            // xnb/ginb reads for THIS wave are complete (MFMA consumed them).
            // C layout: row e = mt*16 + kg*4 + r, col f = nt*16 + m
#pragma unroll
            for (int r = 0; r < 4; r++) {
                int eA = kg * 4 + r, eB = 16 + kg * 4 + r;
                actb[eA * 264 + h * 32 + m]      = f2b(fmaxf(g00[r], 0.f) * v00[r]);
                actb[eA * 264 + h * 32 + 16 + m] = f2b(fmaxf(g01[r], 0.f) * v01[r]);
                actb[eB * 264 + h * 32 + m]      = f2b(fmaxf(g10[r], 0.f) * v10[r]);
                actb[eB * 264 + h * 32 + 16 + m] = f2b(fmaxf(g11[r], 0.f) * v11[r]);
            }
        }
    }
    __syncthreads();

    // P6: out_e = act @ Wp^T via MFMA. wave w owns cols [w*64, w*64+64).
    {
        int w = t >> 6, lane = t & 63;
        int m = lane & 15;
        int kg = lane >> 4;
        v4f acc[2][4];
#pragma unroll
        for (int mt = 0; mt < 2; mt++)
#pragma unroll
            for (int nt = 0; nt < 4; nt++) acc[mt][nt] = (v4f){0.f, 0.f, 0.f, 0.f};
#pragma unroll
        for (int kt = 0; kt < 8; kt++) {
            int k0 = kt * 32 + kg * 8;
            v8bf a0 = *(const v8bf*)&actb[(m) * 264 + k0];
            v8bf a1 = *(const v8bf*)&actb[(16 + m) * 264 + k0];
#pragma unroll
            for (int nt = 0; nt < 4; nt++) {
                int j = w * 64 + nt * 16 + m;  // B[k][j] = Wp[j][k]
                v8bf b = *(const v8bf*)&Wpb[j * 256 + k0];
                acc[0][nt] = __builtin_amdgcn_mfma_f32_16x16x32_bf16(a0, b, acc[0][nt], 0, 0, 0);
                acc[1][nt] = __builtin_amdgcn_mfma_f32_16x16x32_bf16(a1, b, acc[1][nt], 0, 0, 0);
            }
        }
        // scatter: C row e = mt*16 + kg*4 + r, col j = w*64 + nt*16 + m
#pragma unroll
        for (int mt = 0; mt < 2; mt++) {
#pragma unroll
            for (int r = 0; r < 4; r++) {
                int e = mt * 16 + kg * 4 + r;
                if (e < ne) {
                    float* dst = agg + (size_t)tgt_s[e] * WID + w * 64 + m;
#pragma unroll
                    for (int nt = 0; nt < 4; nt++)
                        atomicAdd(dst + nt * 16, acc[mt][nt][r]);
                }
            }
        }
    }
}

// ---------- final degree rescale ----------
__global__ void rescale_k(const float* __restrict__ agg, const float* __restrict__ deg,
                          const float* __restrict__ dp, float* __restrict__ out, int N) {
    int n = blockIdx.x;
    int j = threadIdx.x;
    out[(size_t)n * WID + j] = powf(deg[n], dp[j]) * agg[(size_t)n * WID + j];
}

extern "C" void kernel_launch(void* const* d_in, const int* in_sizes, int n_in,
                              void* d_out, int out_size, void* d_ws, size_t ws_size,
                              hipStream_t stream) {
    const float* x    = (const float*)d_in[0];
    const float* deg  = (const float*)d_in[1];
    const int*   eidx = (const int*)d_in[2];
    const int*   eatt = (const int*)d_in[3];
    const float* Wsrc = (const float*)d_in[4];
    const float* Wtgt = (const float*)d_in[5];
    const float* emb  = (const float*)d_in[6];
    const float* Wg   = (const float*)d_in[7];
    const float* Wv   = (const float*)d_in[8];
    const float* Wp   = (const float*)d_in[9];
    const float* dp   = (const float*)d_in[10];
    int N = in_sizes[0] / WID;
    int E = in_sizes[2] / 2;

    float* ws  = (float*)d_ws;
    float* xs  = ws;                           // N*W
    float* xt  = xs + (size_t)N * WID;         // N*W
    float* agg = xt + (size_t)N * WID;         // N*W
    float* WsT = agg + (size_t)N * WID;        // W*W
    float* WtT = WsT + WID * WID;              // W*W
    unsigned short* Wpb = (unsigned short*)(WtT + WID * WID);  // 65536 bf16
    unsigned short* Wgb = Wpb + 65536;                         // 8192 bf16
    unsigned short* Wvb = Wgb + 8192;                          // 8192 bf16

    hipMemsetAsync(agg, 0, (size_t)N * WID * sizeof(float), stream);
    transpose2_k<<<dim3(8, 8, 2), 256, 0, stream>>>(Wsrc, Wtgt, WsT, WtT);
    cast_k<<<256, 256, 0, stream>>>(Wp, Wg, Wv, Wpb, Wgb, Wvb);
    proj_k<<<(N + 31) / 32, 256, 0, stream>>>(x, WsT, WtT, xs, xt, N);
    edge_k<<<(E + 31) / 32, 256, 0, stream>>>(xs, xt, eidx, eatt, emb, Wgb, Wvb, Wpb, agg, E);
    rescale_k<<<N, 256, 0, stream>>>(agg, deg, dp, (float*)d_out, N);
}

// Round 3
// 469.040 us; speedup vs baseline: 2.8299x; 1.5203x over previous
//
#include <hip/hip_runtime.h>

#define WID 256
#define EPS_GN 1e-5f

typedef __bf16 v8bf __attribute__((ext_vector_type(8)));
typedef float  v4f  __attribute__((ext_vector_type(4)));

__device__ inline unsigned short f2b(float f) {
    unsigned int u = __builtin_bit_cast(unsigned int, f);
    unsigned int r = (u + 0x7fffu + ((u >> 16) & 1u)) >> 16;
    return (unsigned short)r;
}
__device__ inline __bf16 f2bf(float f) {
    unsigned short s = f2b(f);
    return __builtin_bit_cast(__bf16, s);
}

// ---------- cast all weights to bf16 (no transpose: MFMA B-operand wants W rows) ----------
__global__ void cast_k(const float* __restrict__ Wsrc, const float* __restrict__ Wtgt,
                       const float* __restrict__ Wp, const float* __restrict__ Wg,
                       const float* __restrict__ Wv, unsigned short* __restrict__ Wsb,
                       unsigned short* __restrict__ Wtb, unsigned short* __restrict__ Wpb,
                       unsigned short* __restrict__ Wgb, unsigned short* __restrict__ Wvb) {
    int i = blockIdx.x * 256 + threadIdx.x;
    if (i < 65536) { Wsb[i] = f2b(Wsrc[i]); Wtb[i] = f2b(Wtgt[i]); Wpb[i] = f2b(Wp[i]); }
    if (i < 8192)  { Wgb[i] = f2b(Wg[i]);  Wvb[i] = f2b(Wv[i]); }
}

// ---------- node projections via MFMA: xs = x@Wsrc^T, xt = x@Wtgt^T ----------
__global__ __launch_bounds__(256, 2)
void proj_k(const float* __restrict__ x, const unsigned short* __restrict__ Wsb,
            const unsigned short* __restrict__ Wtb, float* __restrict__ xs,
            float* __restrict__ xt, int N) {
    __shared__ unsigned short ab[64 * 264];  // bf16 x-tile [64 nodes][256 k], stride 264
    int t = threadIdx.x;
    int n0 = blockIdx.x * 64;
#pragma unroll
    for (int ch = 0; ch < 16; ch++) {
        int flat = ch * 1024 + t * 4;
        int row = flat >> 8, col = flat & 255;
        int n = n0 + row;
        float4 v = (n < N) ? *(const float4*)&x[(size_t)n * WID + col]
                           : make_float4(0.f, 0.f, 0.f, 0.f);
        unsigned int p0 = (unsigned int)f2b(v.x) | ((unsigned int)f2b(v.y) << 16);
        unsigned int p1 = (unsigned int)f2b(v.z) | ((unsigned int)f2b(v.w) << 16);
        *(uint2*)&ab[row * 264 + col] = make_uint2(p0, p1);
    }
    __syncthreads();
    int w = t >> 6, lane = t & 63, m = lane & 15, kg = lane >> 4;
#pragma unroll
    for (int pass = 0; pass < 2; pass++) {
        const unsigned short* Wb = pass ? Wtb : Wsb;
        float* outp = pass ? xt : xs;
        v4f acc[4][4];
#pragma unroll
        for (int mt = 0; mt < 4; mt++)
#pragma unroll
            for (int nt = 0; nt < 4; nt++) acc[mt][nt] = (v4f){0.f, 0.f, 0.f, 0.f};
#pragma unroll
        for (int kt = 0; kt < 8; kt++) {
            int k0 = kt * 32 + kg * 8;
            v8bf a[4];
#pragma unroll
            for (int mt = 0; mt < 4; mt++)
                a[mt] = *(const v8bf*)&ab[(mt * 16 + m) * 264 + k0];
#pragma unroll
            for (int nt = 0; nt < 4; nt++) {
                int j = w * 64 + nt * 16 + m;
                v8bf b = *(const v8bf*)&Wb[j * 256 + k0];
#pragma unroll
                for (int mt = 0; mt < 4; mt++)
                    acc[mt][nt] = __builtin_amdgcn_mfma_f32_16x16x32_bf16(a[mt], b, acc[mt][nt], 0, 0, 0);
            }
        }
#pragma unroll
        for (int mt = 0; mt < 4; mt++)
#pragma unroll
            for (int r = 0; r < 4; r++) {
                int n = n0 + mt * 16 + kg * 4 + r;
                if (n < N)
#pragma unroll
                    for (int nt = 0; nt < 4; nt++)
                        outp[(size_t)n * WID + w * 64 + nt * 16 + m] = acc[mt][nt][r];
            }
        __syncthreads();  // harmless; keeps ab stable across passes
    }
}

// ---------- fused edge pipeline: gather -> GN -> bag -> gate/val MFMA -> atomic scatter of act ----------
__global__ __launch_bounds__(256, 3)
void edge_k(const float* __restrict__ xs, const float* __restrict__ xt,
            const int* __restrict__ eidx, const int* __restrict__ eattr,
            const float* __restrict__ emb, const unsigned short* __restrict__ Wgb,
            const unsigned short* __restrict__ Wvb, float* __restrict__ aggact, int E) {
    __shared__ float xx[32 * 260];             // fp32, stride 260 (16B-aligned, even bank spread)
    __shared__ unsigned short ginb[32 * 264];  // bf16 xn + bag bias
    __shared__ float mu_s[256], rs_s[256];
    __shared__ int src_s[32], tgt_s[32], attr_s[96];

    int t = threadIdx.x;
    int e0 = blockIdx.x * 32;
    int ne = min(32, E - e0);

    if (t < 32) { src_s[t] = (t < ne) ? eidx[e0 + t] : 0;
                  tgt_s[t] = (t < ne) ? eidx[E + e0 + t] : 0; }
    if (t < 96) attr_s[t] = (t < ne * 3) ? eattr[(size_t)e0 * 3 + t] : 0;
    __syncthreads();

    // P1: vectorized gather xs[src]+xt[tgt] -> xx.  thread -> (edge e=t>>3, chunk c=t&7)
    {
        int e = t >> 3, c = t & 7;
        int s = src_s[e], g = tgt_s[e];
        const float4* ps = (const float4*)&xs[(size_t)s * WID];
        const float4* pt = (const float4*)&xt[(size_t)g * WID];
        bool live = (e < ne);
#pragma unroll
        for (int i = 0; i < 8; i++) {
            int c4 = c + i * 8;  // float4 index 0..63
            float4 a = ps[c4], b = pt[c4];
            float4 v;
            v.x = live ? a.x + b.x : 0.f; v.y = live ? a.y + b.y : 0.f;
            v.z = live ? a.z + b.z : 0.f; v.w = live ? a.w + b.w : 0.f;
            *(float4*)&xx[e * 260 + c4 * 4] = v;
        }
    }
    __syncthreads();

    // P2: group stats, one (e,h) per thread, rotated reads
    {
        int e = t >> 3, h = t & 7;
        int base = e * 260 + h * 32;
        float sum = 0.f, sq = 0.f;
#pragma unroll
        for (int i = 0; i < 32; i++) {
            int d = (t + i) & 31;
            float v = xx[base + d];
            sum += v; sq += v * v;
        }
        float mu = sum * (1.f / 32.f);
        float var = sq * (1.f / 32.f) - mu * mu;
        mu_s[t] = mu;
        rs_s[t] = rsqrtf(var + EPS_GN);
    }
    __syncthreads();

    // P4: normalize xx in place (fp32) + write bf16 gate input (xn + bag bias). column t.
    {
        int h = t >> 5;
        for (int e = 0; e < 32; e++) {
            int si = e * 8 + h;
            float xn = (xx[e * 260 + t] - mu_s[si]) * rs_s[si];
            xx[e * 260 + t] = xn;
            float b = 0.f; int cnt = 0;
#pragma unroll
            for (int c = 0; c < 3; c++) {
                int idx = attr_s[e * 3 + c];
                if (idx != 0) { b += emb[idx * WID + t]; cnt++; }
            }
            b *= (cnt > 0) ? (1.f / (float)cnt) : 1.f;
            ginb[e * 264 + t] = f2b(xn + b);
        }
    }
    __syncthreads();

    // P5: gate/val per-head MFMA; scatter act directly from accumulators.
    {
        int w = t >> 6, lane = t & 63;
        int m = lane & 15, kg = lane >> 4;
#pragma unroll
        for (int hh = 0; hh < 2; hh++) {
            int h = w * 2 + hh;
            // val A-frags from fp32 xx (convert in-register)
            v8bf av0, av1;
            {
                const float* p0 = &xx[m * 260 + h * 32 + kg * 8];
                const float* p1 = &xx[(16 + m) * 260 + h * 32 + kg * 8];
                float4 x0 = *(const float4*)p0, x1 = *(const float4*)(p0 + 4);
                float4 y0 = *(const float4*)p1, y1 = *(const float4*)(p1 + 4);
                av0[0]=f2bf(x0.x); av0[1]=f2bf(x0.y); av0[2]=f2bf(x0.z); av0[3]=f2bf(x0.w);
                av0[4]=f2bf(x1.x); av0[5]=f2bf(x1.y); av0[6]=f2bf(x1.z); av0[7]=f2bf(x1.w);
                av1[0]=f2bf(y0.x); av1[1]=f2bf(y0.y); av1[2]=f2bf(y0.z); av1[3]=f2bf(y0.w);
                av1[4]=f2bf(y1.x); av1[5]=f2bf(y1.y); av1[6]=f2bf(y1.z); av1[7]=f2bf(y1.w);
            }
            v8bf ag0 = *(const v8bf*)&ginb[m * 264 + h * 32 + kg * 8];
            v8bf ag1 = *(const v8bf*)&ginb[(16 + m) * 264 + h * 32 + kg * 8];
            v8bf bg0 = *(const v8bf*)&Wgb[h * 1024 + m * 32 + kg * 8];
            v8bf bg1 = *(const v8bf*)&Wgb[h * 1024 + (16 + m) * 32 + kg * 8];
            v8bf bv0 = *(const v8bf*)&Wvb[h * 1024 + m * 32 + kg * 8];
            v8bf bv1 = *(const v8bf*)&Wvb[h * 1024 + (16 + m) * 32 + kg * 8];
            v4f z = {0.f, 0.f, 0.f, 0.f};
            v4f g00 = __builtin_amdgcn_mfma_f32_16x16x32_bf16(ag0, bg0, z, 0, 0, 0);
            v4f g01 = __builtin_amdgcn_mfma_f32_16x16x32_bf16(ag0, bg1, z, 0, 0, 0);
            v4f g10 = __builtin_amdgcn_mfma_f32_16x16x32_bf16(ag1, bg0, z, 0, 0, 0);
            v4f g11 = __builtin_amdgcn_mfma_f32_16x16x32_bf16(ag1, bg1, z, 0, 0, 0);
            v4f v00 = __builtin_amdgcn_mfma_f32_16x16x32_bf16(av0, bv0, z, 0, 0, 0);
            v4f v01 = __builtin_amdgcn_mfma_f32_16x16x32_bf16(av0, bv1, z, 0, 0, 0);
            v4f v10 = __builtin_amdgcn_mfma_f32_16x16x32_bf16(av1, bv0, z, 0, 0, 0);
            v4f v11 = __builtin_amdgcn_mfma_f32_16x16x32_bf16(av1, bv1, z, 0, 0, 0);
            // C layout: row e = tile*16 + kg*4 + r, col f = h*32 + (ntile*16 + m)
#pragma unroll
            for (int r = 0; r < 4; r++) {
                int eA = kg * 4 + r, eB = eA + 16;
                if (eA < ne) {
                    float* dst = aggact + (size_t)tgt_s[eA] * WID + h * 32 + m;
                    atomicAdd(dst,      fmaxf(g00[r], 0.f) * v00[r]);
                    atomicAdd(dst + 16, fmaxf(g01[r], 0.f) * v01[r]);
                }
                if (eB < ne) {
                    float* dst = aggact + (size_t)tgt_s[eB] * WID + h * 32 + m;
                    atomicAdd(dst,      fmaxf(g10[r], 0.f) * v10[r]);
                    atomicAdd(dst + 16, fmaxf(g11[r], 0.f) * v11[r]);
                }
            }
        }
    }
}

// ---------- post: out = deg^p ⊙ (aggact @ Wp^T), MFMA + fused rescale ----------
__global__ __launch_bounds__(256, 2)
void post_k(const float* __restrict__ aggact, const unsigned short* __restrict__ Wpb,
            const float* __restrict__ deg, const float* __restrict__ dp,
            float* __restrict__ out, int N) {
    __shared__ unsigned short ab[64 * 264];
    __shared__ float degl[64];
    int t = threadIdx.x;
    int n0 = blockIdx.x * 64;
#pragma unroll
    for (int ch = 0; ch < 16; ch++) {
        int flat = ch * 1024 + t * 4;
        int row = flat >> 8, col = flat & 255;
        int n = n0 + row;
        float4 v = (n < N) ? *(const float4*)&aggact[(size_t)n * WID + col]
                           : make_float4(0.f, 0.f, 0.f, 0.f);
        unsigned int p0 = (unsigned int)f2b(v.x) | ((unsigned int)f2b(v.y) << 16);
        unsigned int p1 = (unsigned int)f2b(v.z) | ((unsigned int)f2b(v.w) << 16);
        *(uint2*)&ab[row * 264 + col] = make_uint2(p0, p1);
    }
    if (t < 64) {
        int n = n0 + t;
        degl[t] = (n < N) ? log2f(deg[n]) : 0.f;
    }
    __syncthreads();
    int w = t >> 6, lane = t & 63, m = lane & 15, kg = lane >> 4;
    v4f acc[4][4];
#pragma unroll
    for (int mt = 0; mt < 4; mt++)
#pragma unroll
        for (int nt = 0; nt < 4; nt++) acc[mt][nt] = (v4f){0.f, 0.f, 0.f, 0.f};
#pragma unroll
    for (int kt = 0; kt < 8; kt++) {
        int k0 = kt * 32 + kg * 8;
        v8bf a[4];
#pragma unroll
        for (int mt = 0; mt < 4; mt++)
            a[mt] = *(const v8bf*)&ab[(mt * 16 + m) * 264 + k0];
#pragma unroll
        for (int nt = 0; nt < 4; nt++) {
            int j = w * 64 + nt * 16 + m;
            v8bf b = *(const v8bf*)&Wpb[j * 256 + k0];
#pragma unroll
            for (int mt = 0; mt < 4; mt++)
                acc[mt][nt] = __builtin_amdgcn_mfma_f32_16x16x32_bf16(a[mt], b, acc[mt][nt], 0, 0, 0);
        }
    }
    float dpv[4];
#pragma unroll
    for (int nt = 0; nt < 4; nt++) dpv[nt] = dp[w * 64 + nt * 16 + m];
#pragma unroll
    for (int mt = 0; mt < 4; mt++)
#pragma unroll
        for (int r = 0; r < 4; r++) {
            int row = mt * 16 + kg * 4 + r;
            int n = n0 + row;
            if (n < N) {
                float ld = degl[row];
#pragma unroll
                for (int nt = 0; nt < 4; nt++)
                    out[(size_t)n * WID + w * 64 + nt * 16 + m] =
                        exp2f(dpv[nt] * ld) * acc[mt][nt][r];
            }
        }
}

extern "C" void kernel_launch(void* const* d_in, const int* in_sizes, int n_in,
                              void* d_out, int out_size, void* d_ws, size_t ws_size,
                              hipStream_t stream) {
    const float* x    = (const float*)d_in[0];
    const float* deg  = (const float*)d_in[1];
    const int*   eidx = (const int*)d_in[2];
    const int*   eatt = (const int*)d_in[3];
    const float* Wsrc = (const float*)d_in[4];
    const float* Wtgt = (const float*)d_in[5];
    const float* emb  = (const float*)d_in[6];
    const float* Wg   = (const float*)d_in[7];
    const float* Wv   = (const float*)d_in[8];
    const float* Wp   = (const float*)d_in[9];
    const float* dp   = (const float*)d_in[10];
    int N = in_sizes[0] / WID;
    int E = in_sizes[2] / 2;

    float* ws     = (float*)d_ws;
    float* xs     = ws;                         // N*W
    float* xt     = xs + (size_t)N * WID;       // N*W
    float* aggact = xt + (size_t)N * WID;       // N*W
    unsigned short* Wsb = (unsigned short*)(aggact + (size_t)N * WID);
    unsigned short* Wtb = Wsb + 65536;
    unsigned short* Wpb = Wtb + 65536;
    unsigned short* Wgb = Wpb + 65536;
    unsigned short* Wvb = Wgb + 8192;

    hipMemsetAsync(aggact, 0, (size_t)N * WID * sizeof(float), stream);
    cast_k<<<256, 256, 0, stream>>>(Wsrc, Wtgt, Wp, Wg, Wv, Wsb, Wtb, Wpb, Wgb, Wvb);
    proj_k<<<(N + 63) / 64, 256, 0, stream>>>(x, Wsb, Wtb, xs, xt, N);
    edge_k<<<(E + 31) / 32, 256, 0, stream>>>(xs, xt, eidx, eatt, emb, Wgb, Wvb, aggact, E);
    post_k<<<(N + 63) / 64, 256, 0, stream>>>(aggact, Wpb, deg, dp, (float*)d_out, N);
}